// Round 1
// baseline (457.978 us; speedup 1.0000x reference)
//
#include <hip/hip_runtime.h>
#include <math.h>

#define D 2048
#define M 32
#define SCALE 0.022097086912079608f  // 1/sqrt(2048)

// ws layout (floats):
//   [0      , 65536)  WqmT[m][d]  = SCALE * sum_e Wq[e][d]*mem[m][e]
//   [65536  , 131072) Wm2 [m][e]  = sum_d mem[m][d]*Wm[e][d]
//   [131072 , 131104) cq_s[m]     = SCALE * sum_e bq[e]*mem[m][e]

// ---------------- precompute: WqmT ----------------
__global__ __launch_bounds__(256) void k_wqmt(const float* __restrict__ Wq,
                                              const float* __restrict__ mem,
                                              float* __restrict__ WqmT) {
    __shared__ float memL[M * 128];
    const int t  = threadIdx.x;
    const int dc = blockIdx.x;   // 0..7   (d chunk of 256)
    const int ec = blockIdx.y;   // 0..15  (e chunk of 128)
    const int d  = dc * 256 + t;
    {
        const float4* mg = (const float4*)mem;
        float4* ml = (float4*)memL;
#pragma unroll
        for (int q = 0; q < 4; ++q) {
            int i4 = t + 256 * q;          // 0..1023
            int m = i4 >> 5, c4 = i4 & 31; // 32 float4 per m-row
            ml[i4] = mg[m * 512 + ec * 32 + c4];
        }
    }
    __syncthreads();
    float acc[M];
#pragma unroll
    for (int m = 0; m < M; ++m) acc[m] = 0.f;
    const float4* ml4 = (const float4*)memL;
    for (int ee = 0; ee < 128; ee += 4) {
        float q0 = Wq[(ec * 128 + ee + 0) * D + d];
        float q1 = Wq[(ec * 128 + ee + 1) * D + d];
        float q2 = Wq[(ec * 128 + ee + 2) * D + d];
        float q3 = Wq[(ec * 128 + ee + 3) * D + d];
#pragma unroll
        for (int m = 0; m < M; ++m) {
            float4 mv = ml4[m * 32 + (ee >> 2)];
            acc[m] = fmaf(q0, mv.x, fmaf(q1, mv.y, fmaf(q2, mv.z, fmaf(q3, mv.w, acc[m]))));
        }
    }
#pragma unroll
    for (int m = 0; m < M; ++m) atomicAdd(&WqmT[m * D + d], acc[m] * SCALE);
}

// ---------------- precompute: Wm2 ----------------
__global__ __launch_bounds__(256) void k_wm2(const float* __restrict__ Wm,
                                             const float* __restrict__ mem,
                                             float* __restrict__ Wm2) {
    __shared__ float tile[64 * 65];   // Wm tile, padded
    __shared__ float memL[M * 64];
    const int t  = threadIdx.x;
    const int et = blockIdx.x;   // 0..31 e-tile of 64
    const int dq = blockIdx.y;   // 0..3  d-quarter of 512
    const int e0 = et * 64;
    const int el = t & 63, mg = t >> 6;
    float acc[8];
#pragma unroll
    for (int j = 0; j < 8; ++j) acc[j] = 0.f;
    for (int ds = 0; ds < 8; ++ds) {
        const int d0 = dq * 512 + ds * 64;
        // stage Wm tile 64x64 (coalesced), transposed-friendly padded LDS
#pragma unroll
        for (int q = 0; q < 4; ++q) {
            int i  = (t >> 4) + 16 * q;  // row 0..63
            int c4 = t & 15;             // float4 col
            float4 v = *(const float4*)&Wm[(e0 + i) * D + d0 + 4 * c4];
            tile[i * 65 + 4 * c4 + 0] = v.x;
            tile[i * 65 + 4 * c4 + 1] = v.y;
            tile[i * 65 + 4 * c4 + 2] = v.z;
            tile[i * 65 + 4 * c4 + 3] = v.w;
        }
        // stage mem chunk 32x64
#pragma unroll
        for (int q = 0; q < 2; ++q) {
            int i4 = t + 256 * q;           // 0..511
            int m = i4 >> 4, c4 = i4 & 15;  // 16 float4 per m-row
            *(float4*)&memL[m * 64 + 4 * c4] = *(const float4*)&mem[m * D + d0 + 4 * c4];
        }
        __syncthreads();
        const float4* ml4 = (const float4*)memL;
        for (int dd = 0; dd < 64; dd += 4) {
            float t0 = tile[el * 65 + dd + 0];
            float t1 = tile[el * 65 + dd + 1];
            float t2 = tile[el * 65 + dd + 2];
            float t3 = tile[el * 65 + dd + 3];
#pragma unroll
            for (int j = 0; j < 8; ++j) {
                float4 mv = ml4[(mg * 8 + j) * 16 + (dd >> 2)];
                acc[j] = fmaf(t0, mv.x, fmaf(t1, mv.y, fmaf(t2, mv.z, fmaf(t3, mv.w, acc[j]))));
            }
        }
        __syncthreads();
    }
#pragma unroll
    for (int j = 0; j < 8; ++j) atomicAdd(&Wm2[(mg * 8 + j) * D + e0 + el], acc[j]);
}

// ---------------- precompute: cq_s ----------------
__global__ __launch_bounds__(256) void k_cq(const float* __restrict__ bq,
                                            const float* __restrict__ mem,
                                            float* __restrict__ cqs) {
    __shared__ float red[256 * 32];
    const int t = threadIdx.x;
    float acc[M];
#pragma unroll
    for (int m = 0; m < M; ++m) acc[m] = 0.f;
    for (int e = t; e < D; e += 256) {
        float b = bq[e];
#pragma unroll
        for (int m = 0; m < M; ++m) acc[m] = fmaf(b, mem[m * D + e], acc[m]);
    }
#pragma unroll
    for (int m = 0; m < M; ++m) red[t * 32 + m] = acc[m];
    __syncthreads();
    if (t < 32) {
        float s = 0.f;
        for (int i = 0; i < 256; ++i) s += red[i * 32 + t];
        cqs[t] = s * SCALE;
    }
}

// ---------------- fused main ----------------
__global__ __launch_bounds__(256, 2) void k_main(const float* __restrict__ x,
                                                 const float* __restrict__ WqmT,
                                                 const float* __restrict__ Wm2,
                                                 const float* __restrict__ cqs,
                                                 const float* __restrict__ bm,
                                                 float* __restrict__ out) {
    __shared__ float4 ldsW[M * 64];  // 32KB: one 256-wide d/e chunk of a [32][2048] panel
    const int t    = threadIdx.x;
    const int wv   = t >> 6;
    const int lane = t & 63;
    const long row0 = (long)blockIdx.x * 8 + wv * 2;
    const float4* x40 = (const float4*)(x + row0 * D);
    const float4* x41 = (const float4*)(x + (row0 + 1) * D);
    // x held in registers: 2 rows x 8 float4 per lane, d = 4*lane + 256*j
    float4 xr0[8], xr1[8];
#pragma unroll
    for (int j = 0; j < 8; ++j) { xr0[j] = x40[lane + 64 * j]; xr1[j] = x41[lane + 64 * j]; }

    float acc0[M], acc1[M];
#pragma unroll
    for (int m = 0; m < M; ++m) { acc0[m] = 0.f; acc1[m] = 0.f; }

    const float4* Wg = (const float4*)WqmT;
#pragma unroll
    for (int c = 0; c < 8; ++c) {
        {
            const int m = t >> 3, b4 = t & 7;
#pragma unroll
            for (int i = 0; i < 8; ++i)
                ldsW[m * 64 + b4 + 8 * i] = Wg[m * 512 + c * 64 + b4 + 8 * i];
        }
        __syncthreads();
        const float4 xa = xr0[c], xb = xr1[c];
#pragma unroll
        for (int m = 0; m < M; ++m) {
            float4 v = ldsW[m * 64 + lane];
            acc0[m] = fmaf(xa.x, v.x, fmaf(xa.y, v.y, fmaf(xa.z, v.z, fmaf(xa.w, v.w, acc0[m]))));
            acc1[m] = fmaf(xb.x, v.x, fmaf(xb.y, v.y, fmaf(xb.z, v.z, fmaf(xb.w, v.w, acc1[m]))));
        }
        __syncthreads();
    }

    // reduce partial dots across the 64 lanes; lane (l&31)==m keeps attn[r][m]
    float at0 = 0.f, at1 = 0.f;
#pragma unroll
    for (int m = 0; m < M; ++m) {
        float a0 = acc0[m], a1 = acc1[m];
#pragma unroll
        for (int s = 1; s < 64; s <<= 1) {
            a0 += __shfl_xor(a0, s, 64);
            a1 += __shfl_xor(a1, s, 64);
        }
        if ((lane & 31) == m) { at0 = a0; at1 = a1; }
    }
    const float cq = cqs[lane & 31];
    at0 += cq; at1 += cq;

    // softmax across the 32-lane m dimension (replicated in both half-waves)
    float mx0 = at0, mx1 = at1;
#pragma unroll
    for (int s = 1; s < 32; s <<= 1) {
        mx0 = fmaxf(mx0, __shfl_xor(mx0, s, 32));
        mx1 = fmaxf(mx1, __shfl_xor(mx1, s, 32));
    }
    float e0 = expf(at0 - mx0), e1 = expf(at1 - mx1);
    float s0 = e0, s1 = e1;
#pragma unroll
    for (int s = 1; s < 32; s <<= 1) {
        s0 += __shfl_xor(s0, s, 32);
        s1 += __shfl_xor(s1, s, 32);
    }
    const float w0 = e0 / s0, w1 = e1 / s1;  // lane holds w[row][lane&31]

    // phase B: out = x + bm + w @ Wm2
    const float4* W2g  = (const float4*)Wm2;
    const float4* bm4p = (const float4*)bm;
    float* o0p = out + row0 * D;
    float* o1p = out + (row0 + 1) * D;
#pragma unroll
    for (int c = 0; c < 8; ++c) {
        {
            const int m = t >> 3, b4 = t & 7;
#pragma unroll
            for (int i = 0; i < 8; ++i)
                ldsW[m * 64 + b4 + 8 * i] = W2g[m * 512 + c * 64 + b4 + 8 * i];
        }
        __syncthreads();
        float4 bmv = bm4p[lane + 64 * c];
        float4 o0 = xr0[c], o1 = xr1[c];
        o0.x += bmv.x; o0.y += bmv.y; o0.z += bmv.z; o0.w += bmv.w;
        o1.x += bmv.x; o1.y += bmv.y; o1.z += bmv.z; o1.w += bmv.w;
#pragma unroll
        for (int m = 0; m < M; ++m) {
            float wm0 = __shfl(w0, m, 32);
            float wm1 = __shfl(w1, m, 32);
            float4 v = ldsW[m * 64 + lane];
            o0.x = fmaf(wm0, v.x, o0.x); o0.y = fmaf(wm0, v.y, o0.y);
            o0.z = fmaf(wm0, v.z, o0.z); o0.w = fmaf(wm0, v.w, o0.w);
            o1.x = fmaf(wm1, v.x, o1.x); o1.y = fmaf(wm1, v.y, o1.y);
            o1.z = fmaf(wm1, v.z, o1.z); o1.w = fmaf(wm1, v.w, o1.w);
        }
        *(float4*)(o0p + 4 * lane + 256 * c) = o0;
        *(float4*)(o1p + 4 * lane + 256 * c) = o1;
        __syncthreads();
    }
}

extern "C" void kernel_launch(void* const* d_in, const int* in_sizes, int n_in,
                              void* d_out, int out_size, void* d_ws, size_t ws_size,
                              hipStream_t stream) {
    const float* x   = (const float*)d_in[0];
    const float* mem = (const float*)d_in[1];
    const float* Wq  = (const float*)d_in[2];
    const float* bq  = (const float*)d_in[3];
    const float* Wm  = (const float*)d_in[4];
    const float* bm  = (const float*)d_in[5];
    float* out = (float*)d_out;

    const size_t need = (size_t)(2 * M * D + M) * sizeof(float);
    if (ws_size < need) return;  // workspace too small — nothing sane to do

    float* WqmT = (float*)d_ws;
    float* Wm2  = WqmT + M * D;
    float* cq   = Wm2 + M * D;

    // zero the atomic accumulators (ws is poisoned 0xAA before every launch)
    hipMemsetAsync(d_ws, 0, (size_t)(2 * M * D) * sizeof(float), stream);

    k_wqmt<<<dim3(8, 16), 256, 0, stream>>>(Wq, mem, WqmT);
    k_wm2 <<<dim3(32, 4), 256, 0, stream>>>(Wm, mem, Wm2);
    k_cq  <<<1, 256, 0, stream>>>(bq, mem, cq);

    k_main<<<2048, 256, 0, stream>>>(x, WqmT, Wm2, cq, bm, out);
}